// Round 2
// baseline (686.597 us; speedup 1.0000x reference)
//
#include <hip/hip_runtime.h>
#include <hip/hip_bf16.h>
#include <math.h>

#define HDIM 512
#define LSEQ 1024
#define BSZ  4

typedef __attribute__((ext_vector_type(8))) short short8;
typedef __attribute__((ext_vector_type(4))) float floatx4;

// ---------------- LayerNorm: one wave per (b,t) row ----------------
__global__ __launch_bounds__(64) void ln_kernel(const float* __restrict__ x,
    const float* __restrict__ w, const float* __restrict__ b, float* __restrict__ xn) {
  int row = blockIdx.x;           // b*L + t   (4096 rows)
  int lane = threadIdx.x;
  const float* xr = x + (size_t)row * HDIM;
  float4 v0 = ((const float4*)xr)[lane];
  float4 v1 = ((const float4*)xr)[lane + 64];
  float s  = v0.x + v0.y + v0.z + v0.w + v1.x + v1.y + v1.z + v1.w;
  float ss = v0.x*v0.x + v0.y*v0.y + v0.z*v0.z + v0.w*v0.w
           + v1.x*v1.x + v1.y*v1.y + v1.z*v1.z + v1.w*v1.w;
  #pragma unroll
  for (int m = 1; m < 64; m <<= 1) { s += __shfl_xor(s, m); ss += __shfl_xor(ss, m); }
  float mu   = s * (1.0f / HDIM);
  float var  = ss * (1.0f / HDIM) - mu * mu;
  float rstd = rsqrtf(var + 1e-5f);
  float4 w0 = ((const float4*)w)[lane];
  float4 w1 = ((const float4*)w)[lane + 64];
  float4 b0 = ((const float4*)b)[lane];
  float4 b1 = ((const float4*)b)[lane + 64];
  float4 o0, o1;
  o0.x = (v0.x - mu) * rstd * w0.x + b0.x;
  o0.y = (v0.y - mu) * rstd * w0.y + b0.y;
  o0.z = (v0.z - mu) * rstd * w0.z + b0.z;
  o0.w = (v0.w - mu) * rstd * w0.w + b0.w;
  o1.x = (v1.x - mu) * rstd * w1.x + b1.x;
  o1.y = (v1.y - mu) * rstd * w1.y + b1.y;
  o1.z = (v1.z - mu) * rstd * w1.z + b1.z;
  o1.w = (v1.w - mu) * rstd * w1.w + b1.w;
  float* xo = xn + (size_t)row * HDIM;
  ((float4*)xo)[lane] = o0;
  ((float4*)xo)[lane + 64] = o1;
}

// ---------------- DPLR setup (1 wave): dense Ab = diag(dab)+u r^T, Bb ----------------
__global__ __launch_bounds__(64) void setup_kernel(
    const float* __restrict__ lre, const float* __restrict__ lim,
    const float* __restrict__ pre, const float* __restrict__ pim,
    const float* __restrict__ bre, const float* __restrict__ bim,
    const float* __restrict__ logstep, float* __restrict__ scr) {
  int n = threadIdx.x;
  float step = expf(logstep[0]);
  float g = 2.0f / step;
  float lr = lre[n], li = lim[n];
  float pr = pre[n], pi = pim[n];
  float br = bre[n], bi = bim[n];
  // dinv = 1/(g - lam)
  float den  = (g - lr) * (g - lr) + li * li;
  float dinr = (g - lr) / den, dini = li / den;
  // dab = (g + lam) * dinv
  float dabr = (g + lr) * dinr - li * dini;
  float dabi = (g + lr) * dini + li * dinr;
  // u = dinv * p
  float ur = dinr * pr - dini * pi;
  float ui = dinr * pi + dini * pr;
  // q = conj(p) * dinv
  float qr = pr * dinr + pi * dini;
  float qi = pr * dini - pi * dinr;
  // beta = sum |p|^2 * dinv ; gamma = sum q * b
  float pm2 = pr * pr + pi * pi;
  float betr = pm2 * dinr, beti = pm2 * dini;
  float gar = qr * br - qi * bi;
  float gai = qr * bi + qi * br;
  #pragma unroll
  for (int m = 1; m < 64; m <<= 1) {
    betr += __shfl_xor(betr, m); beti += __shfl_xor(beti, m);
    gar  += __shfl_xor(gar, m);  gai  += __shfl_xor(gai, m);
  }
  float obr = 1.0f + betr, obi = beti;
  float ob2 = obr * obr + obi * obi;
  // k = -2g/(1+beta);  r = k*q
  float kr = -2.0f * g * obr / ob2;
  float ki =  2.0f * g * obi / ob2;
  float rr = kr * qr - ki * qi;
  float ri = kr * qi + ki * qr;
  // tg = gamma/(1+beta);  Bb = 2*(dinv*b - u*tg)
  float tgr = (gar * obr + gai * obi) / ob2;
  float tgi = (gai * obr - gar * obi) / ob2;
  float dbr = dinr * br - dini * bi;
  float dbi = dinr * bi + dini * br;
  float Bbr = 2.0f * (dbr - (ur * tgr - ui * tgi));
  float Bbi = 2.0f * (dbi - (ur * tgi + ui * tgr));
  float2* scrA = (float2*)scr;
  float2* scrB = scrA + 4096;
  float2 bb; bb.x = Bbr; bb.y = Bbi;
  scrB[n] = bb;
  for (int m = 0; m < 64; m++) {
    float rmr = __shfl(rr, m), rmi = __shfl(ri, m);
    float2 e;
    e.x = ur * rmr - ui * rmi;
    e.y = ur * rmi + ui * rmr;
    if (m == n) { e.x += dabr; e.y += dabi; }
    scrA[n * 64 + m] = e;
  }
}

// ---------------- K[m] = Re(c^T Ab^m Bb) for m=0..1023, one 1024-thr block ----------------
__global__ __launch_bounds__(1024) void power_kernel(const float* __restrict__ scr,
    const float* __restrict__ cre, const float* __restrict__ cim,
    float* __restrict__ Kout) {
  __shared__ float2 M[64 * 64];     // Ab, then in-place squared to Ab^32
  __shared__ float2 Wv[32 * 64];    // W_b = Ab^b Bb
  __shared__ float2 Rv[2][64];      // R_a = c^T (Ab^32)^a, double-buffered
  int tid = threadIdx.x;
  const float2* scrA = (const float2*)scr;
  for (int e = tid; e < 4096; e += 1024) M[e] = scrA[e];
  if (tid < 64) Wv[tid] = scrA[4096 + tid];
  __syncthreads();
  int n16 = tid >> 4, g16 = tid & 15;   // 64 outputs x 16 partials (in-wave reduce)
  // W chain: W_{b+1} = Ab * W_b
  for (int b = 0; b < 31; b++) {
    float2 acc; acc.x = 0.f; acc.y = 0.f;
    #pragma unroll
    for (int i = 0; i < 4; i++) {
      int k = g16 * 4 + i;
      float2 a = M[n16 * 64 + k];
      float2 w = Wv[b * 64 + k];
      acc.x += a.x * w.x - a.y * w.y;
      acc.y += a.x * w.y + a.y * w.x;
    }
    #pragma unroll
    for (int m2 = 1; m2 < 16; m2 <<= 1) {
      acc.x += __shfl_xor(acc.x, m2);
      acc.y += __shfl_xor(acc.y, m2);
    }
    if (g16 == 0) Wv[(b + 1) * 64 + n16] = acc;
    __syncthreads();
  }
  // 5 in-place squarings: M <- M^2 (register-staged)
  for (int sq = 0; sq < 5; sq++) {
    float2 o[4];
    #pragma unroll
    for (int e4 = 0; e4 < 4; e4++) {
      int e = tid + e4 * 1024;
      int i = e >> 6, j = e & 63;
      float2 acc; acc.x = 0.f; acc.y = 0.f;
      for (int k = 0; k < 64; k++) {
        float2 a = M[i * 64 + k], b2 = M[k * 64 + j];
        acc.x += a.x * b2.x - a.y * b2.y;
        acc.y += a.x * b2.y + a.y * b2.x;
      }
      o[e4] = acc;
    }
    __syncthreads();
    #pragma unroll
    for (int e4 = 0; e4 < 4; e4++) M[tid + e4 * 1024] = o[e4];
    __syncthreads();
  }
  // R chain + K rows: K[a*32+b] = Re(R_a . W_b)
  if (tid < 64) { float2 cc; cc.x = cre[tid]; cc.y = cim[tid]; Rv[0][tid] = cc; }
  __syncthreads();
  int b32 = tid >> 5, g32 = tid & 31;   // 32 K-entries x 32 partials (in-wave reduce)
  for (int a = 0; a < 32; a++) {
    const float2* R = Rv[a & 1];
    float s = 0.f;
    #pragma unroll
    for (int i = 0; i < 2; i++) {
      int k = g32 * 2 + i;
      float2 r = R[k];
      float2 w = Wv[b32 * 64 + k];
      s += r.x * w.x - r.y * w.y;
    }
    #pragma unroll
    for (int m2 = 1; m2 < 32; m2 <<= 1) s += __shfl_xor(s, m2);
    if (g32 == 0) Kout[a * 32 + b32] = s;
    if (a < 31) {
      // R_{a+1}[m] = sum_k R_a[k] * M32[k][m]
      float2 acc; acc.x = 0.f; acc.y = 0.f;
      #pragma unroll
      for (int i = 0; i < 4; i++) {
        int k = g16 * 4 + i;
        float2 r = R[k];
        float2 mm = M[k * 64 + n16];
        acc.x += r.x * mm.x - r.y * mm.y;
        acc.y += r.x * mm.y + r.y * mm.x;
      }
      #pragma unroll
      for (int m2 = 1; m2 < 16; m2 <<= 1) {
        acc.x += __shfl_xor(acc.x, m2);
        acc.y += __shfl_xor(acc.y, m2);
      }
      if (g16 == 0) Rv[(a + 1) & 1][n16] = acc;
    }
    __syncthreads();
  }
}

// ---------------- Toeplitz build: T[t][tau] = K[t-tau] (hi/lo bf16 split) ----------------
__global__ __launch_bounds__(256) void toeplitz_kernel(const float* __restrict__ K,
    ushort* __restrict__ Thi, ushort* __restrict__ Tlo) {
  int t = blockIdx.x;
  int tau0 = threadIdx.x * 4;
  ushort4 hi, lo;
  ushort* hp = (ushort*)&hi; ushort* lp = (ushort*)&lo;
  #pragma unroll
  for (int i = 0; i < 4; i++) {
    int tau = tau0 + i;
    float v = (tau <= t) ? K[t - tau] : 0.f;
    __hip_bfloat16 h = __float2bfloat16(v);
    float rem = v - __bfloat162float(h);
    __hip_bfloat16 l = __float2bfloat16(rem);
    hp[i] = *(ushort*)&h; lp[i] = *(ushort*)&l;
  }
  *(ushort4*)&Thi[(size_t)t * 1024 + tau0] = hi;
  *(ushort4*)&Tlo[(size_t)t * 1024 + tau0] = lo;
}

// ---------------- Transpose xn [B,L,H] -> U[c=b*512+h][t] (hi/lo bf16) ----------------
__global__ __launch_bounds__(256) void transpose_kernel(const float* __restrict__ xn,
    ushort* __restrict__ Uhi, ushort* __restrict__ Ulo) {
  __shared__ float tile[64][65];
  int ht = blockIdx.x;   // h tile (8)
  int lt = blockIdx.y;   // l tile (16)
  int b  = blockIdx.z;
  int tid = threadIdx.x;
  #pragma unroll
  for (int q = 0; q < 16; q++) {
    int idx = q * 256 + tid;
    int r = idx >> 6, c = idx & 63;                 // r: l-offset, c: h-offset
    tile[r][c] = xn[((size_t)(b * LSEQ + lt * 64 + r)) * HDIM + ht * 64 + c];
  }
  __syncthreads();
  #pragma unroll
  for (int q = 0; q < 16; q++) {
    int idx = q * 256 + tid;
    int r = idx >> 6, c = idx & 63;                 // r: h-offset, c: l-offset
    float v = tile[c][r];
    __hip_bfloat16 h = __float2bfloat16(v);
    float rem = v - __bfloat162float(h);
    __hip_bfloat16 l = __float2bfloat16(rem);
    size_t off = ((size_t)(b * HDIM + ht * 64 + r)) * LSEQ + lt * 64 + c;
    Uhi[off] = *(ushort*)&h;
    Ulo[off] = *(ushort*)&l;
  }
}

// -------- Conv GEMM: Y[1024x2048] = Thi*Uhi + Tlo*Uhi + Thi*Ulo (K=3x1024) --------
__global__ __launch_bounds__(256) void conv_gemm_kernel(
    const ushort* __restrict__ Thi, const ushort* __restrict__ Tlo,
    const ushort* __restrict__ Uhi, const ushort* __restrict__ Ulo,
    float* __restrict__ Y) {
  __shared__ ushort sA[128 * 32];
  __shared__ ushort sB[128 * 32];
  int tid = threadIdx.x;
  int lane = tid & 63;
  int wv = tid >> 6;
  int wm = wv >> 1, wn = wv & 1;
  int bm = blockIdx.y, bn = blockIdx.x;   // bm<8 (t), bn<16 (c)
  floatx4 acc[4][4] = {};
  int lrow = tid >> 2;
  int lcol = (tid & 3) * 8;
  int fr = lane & 15, fq = (lane >> 4) * 8;
  for (int kt = 0; kt < 96; kt++) {
    int region = kt >> 5;
    int k0 = (kt & 31) * 32;
    const ushort* Ag = ((region == 1) ? Tlo : Thi) + (size_t)(bm * 128) * 1024;
    const ushort* Bg = ((region == 2) ? Ulo : Uhi) + (size_t)(bn * 128) * 1024;
    #pragma unroll
    for (int q = 0; q < 2; q++) {
      int row = lrow + q * 64;
      *(uint4*)&sA[row * 32 + lcol] = *(const uint4*)&Ag[(size_t)row * 1024 + k0 + lcol];
      *(uint4*)&sB[row * 32 + lcol] = *(const uint4*)&Bg[(size_t)row * 1024 + k0 + lcol];
    }
    __syncthreads();
    short8 af[4], bf[4];
    #pragma unroll
    for (int i = 0; i < 4; i++) {
      af[i] = *(const short8*)&sA[(wm * 64 + i * 16 + fr) * 32 + fq];
      bf[i] = *(const short8*)&sB[(wn * 64 + i * 16 + fr) * 32 + fq];
    }
    #pragma unroll
    for (int i = 0; i < 4; i++)
      #pragma unroll
      for (int j = 0; j < 4; j++)
        acc[i][j] = __builtin_amdgcn_mfma_f32_16x16x32_bf16(af[i], bf[j], acc[i][j], 0, 0, 0);
    __syncthreads();
  }
  int row0 = bm * 128 + wm * 64;
  int col0 = bn * 128 + wn * 64;
  int fc = lane & 15, frq = (lane >> 4) * 4;
  #pragma unroll
  for (int i = 0; i < 4; i++)
    #pragma unroll
    for (int j = 0; j < 4; j++)
      #pragma unroll
      for (int r = 0; r < 4; r++)
        Y[(size_t)(row0 + i * 16 + frq + r) * 2048 + col0 + j * 16 + fc] = acc[i][j][r];
}

// ---------------- A-prep (elementwise): A[b,t,h] = gelu(Y[t][b*512+h] + d*xn) ----------------
__global__ __launch_bounds__(256) void aprep_kernel(const float* __restrict__ Y,
    const float* __restrict__ xn, const float* __restrict__ dptr,
    __hip_bfloat16* __restrict__ A) {
  int idx = blockIdx.x * 256 + threadIdx.x;       // 2M
  int h = idx & 511;
  int t = (idx >> 9) & 1023;
  int b = idx >> 19;
  float y = Y[(size_t)t * 2048 + b * 512 + h] + dptr[0] * xn[idx];
  float tnh = tanhf(0.7978845608028654f * (y + 0.044715f * y * y * y));
  float gl = 0.5f * y * (1.0f + tnh);
  A[idx] = __float2bfloat16(gl);
}

// ---------------- Weight convert/stack: Wst[1024][512] bf16 ----------------
__global__ __launch_bounds__(256) void wconv_kernel(const float* __restrict__ w1,
    const float* __restrict__ w2, __hip_bfloat16* __restrict__ Wst) {
  int idx = blockIdx.x * 256 + threadIdx.x;       // 524288
  int n = idx >> 9, k = idx & 511;
  float v = (n < 512) ? w1[n * 512 + k] : w2[(n - 512) * 512 + k];
  Wst[idx] = __float2bfloat16(v);
}

// ---------------- Proj GEMM: C[4096,1024] = A[4096,512] * Wst[1024,512]^T ----------------
__global__ __launch_bounds__(256) void gemm_kernel(const __hip_bfloat16* __restrict__ Abf,
    const __hip_bfloat16* __restrict__ Wst, float* __restrict__ C) {
  __shared__ unsigned short sA[128 * 32];
  __shared__ unsigned short sB[128 * 32];
  int tid = threadIdx.x;
  int lane = tid & 63;
  int wv = tid >> 6;
  int wm = wv >> 1, wn = wv & 1;
  int bm = blockIdx.y, bn = blockIdx.x;
  floatx4 acc[4][4] = {};
  const unsigned short* Ag = (const unsigned short*)Abf + (size_t)(bm * 128) * 512;
  const unsigned short* Bg = (const unsigned short*)Wst + (size_t)(bn * 128) * 512;
  int lrow = tid >> 2;
  int lcol = (tid & 3) * 8;
  int fr = lane & 15, fq = (lane >> 4) * 8;
  for (int kt = 0; kt < 16; kt++) {
    int k0 = kt * 32;
    #pragma unroll
    for (int q = 0; q < 2; q++) {
      int row = lrow + q * 64;
      *(uint4*)&sA[row * 32 + lcol] = *(const uint4*)&Ag[(size_t)row * 512 + k0 + lcol];
      *(uint4*)&sB[row * 32 + lcol] = *(const uint4*)&Bg[(size_t)row * 512 + k0 + lcol];
    }
    __syncthreads();
    short8 af[4], bf[4];
    #pragma unroll
    for (int i = 0; i < 4; i++) {
      af[i] = *(const short8*)&sA[(wm * 64 + i * 16 + fr) * 32 + fq];
      bf[i] = *(const short8*)&sB[(wn * 64 + i * 16 + fr) * 32 + fq];
    }
    #pragma unroll
    for (int i = 0; i < 4; i++)
      #pragma unroll
      for (int j = 0; j < 4; j++)
        acc[i][j] = __builtin_amdgcn_mfma_f32_16x16x32_bf16(af[i], bf[j], acc[i][j], 0, 0, 0);
    __syncthreads();
  }
  int row0 = bm * 128 + wm * 64;
  int col0 = bn * 128 + wn * 64;
  int fc = lane & 15, frq = (lane >> 4) * 4;
  #pragma unroll
  for (int i = 0; i < 4; i++)
    #pragma unroll
    for (int j = 0; j < 4; j++)
      #pragma unroll
      for (int r = 0; r < 4; r++)
        C[(size_t)(row0 + i * 16 + frq + r) * 1024 + col0 + j * 16 + fc] = acc[i][j][r];
}

// ---------------- Final: out = x + (C1 + ob) * sigmoid(C2 + o2b) ----------------
__global__ __launch_bounds__(256) void final_kernel(const float* __restrict__ x,
    const float* __restrict__ C, const float* __restrict__ ob,
    const float* __restrict__ o2b, float* __restrict__ out) {
  int idx = blockIdx.x * 256 + threadIdx.x;
  int i = idx & 511;
  int bt = idx >> 9;
  float c1 = C[(size_t)bt * 1024 + i] + ob[i];
  float c2 = C[(size_t)bt * 1024 + 512 + i] + o2b[i];
  float gate = 1.0f / (1.0f + expf(-c2));
  out[idx] = x[idx] + c1 * gate;
}

extern "C" void kernel_launch(void* const* d_in, const int* in_sizes, int n_in,
                              void* d_out, int out_size, void* d_ws, size_t ws_size,
                              hipStream_t stream) {
  const float* x   = (const float*)d_in[0];
  const float* nw  = (const float*)d_in[1];
  const float* nb  = (const float*)d_in[2];
  const float* lre = (const float*)d_in[3];
  const float* lim = (const float*)d_in[4];
  const float* pre = (const float*)d_in[5];
  const float* pim = (const float*)d_in[6];
  const float* bre = (const float*)d_in[7];
  const float* bim = (const float*)d_in[8];
  const float* cre = (const float*)d_in[9];
  const float* cim = (const float*)d_in[10];
  const float* dsc = (const float*)d_in[11];
  const float* lst = (const float*)d_in[12];
  const float* w1  = (const float*)d_in[13];
  const float* ob  = (const float*)d_in[14];
  const float* w2  = (const float*)d_in[15];
  const float* o2b = (const float*)d_in[16];

  char* ws = (char*)d_ws;
  // Layout (32 MB total, time-multiplexed):
  float* xn   = (float*)(ws);                              // 0..8MB   (live: ln..aprep)
  float* Yc   = (float*)(ws + (size_t)(8  << 20));         // 8..16MB  (conv out; live conv..aprep)
  float* scr  = (float*)(ws + (size_t)(8  << 20));         // reuses Y region (dead before conv)
  float* Kbuf = (float*)(ws + (size_t)(8  << 20) + 65536); // K[1024] (dead before conv)
  ushort* Uhi = (ushort*)(ws + (size_t)(16 << 20));        // 16..20MB
  ushort* Ulo = (ushort*)(ws + (size_t)(20 << 20));        // 20..24MB
  ushort* Thi = (ushort*)(ws + (size_t)(24 << 20));        // 24..26MB
  ushort* Tlo = (ushort*)(ws + (size_t)(26 << 20));        // 26..28MB
  __hip_bfloat16* Abuf = (__hip_bfloat16*)(ws + (size_t)(28 << 20)); // 28..32MB
  __hip_bfloat16* Wst  = (__hip_bfloat16*)(ws + (size_t)(24 << 20)); // reuses Thi (after conv)
  float* C    = (float*)(ws + (size_t)(8 << 20));          // 8..24MB (after aprep)
  float* out  = (float*)d_out;

  ln_kernel<<<dim3(4096), dim3(64), 0, stream>>>(x, nw, nb, xn);
  setup_kernel<<<dim3(1), dim3(64), 0, stream>>>(lre, lim, pre, pim, bre, bim, lst, scr);
  power_kernel<<<dim3(1), dim3(1024), 0, stream>>>(scr, cre, cim, Kbuf);
  toeplitz_kernel<<<dim3(1024), dim3(256), 0, stream>>>(Kbuf, Thi, Tlo);
  transpose_kernel<<<dim3(8, 16, 4), dim3(256), 0, stream>>>(xn, Uhi, Ulo);
  conv_gemm_kernel<<<dim3(16, 8), dim3(256), 0, stream>>>(Thi, Tlo, Uhi, Ulo, Yc);
  wconv_kernel<<<dim3(2048), dim3(256), 0, stream>>>(w1, w2, Wst);
  aprep_kernel<<<dim3(8192), dim3(256), 0, stream>>>(Yc, xn, dsc, Abuf);
  gemm_kernel<<<dim3(8, 32), dim3(256), 0, stream>>>(Abuf, Wst, C);
  final_kernel<<<dim3(8192), dim3(256), 0, stream>>>(x, C, ob, o2b, out);
}

// Round 3
// 308.679 us; speedup vs baseline: 2.2243x; 2.2243x over previous
//
#include <hip/hip_runtime.h>
#include <hip/hip_bf16.h>
#include <math.h>

#define HDIM 512
#define LSEQ 1024
#define BSZ  4

typedef __attribute__((ext_vector_type(8))) short short8;
typedef __attribute__((ext_vector_type(4))) float floatx4;

// ---------------- LayerNorm: one wave per (b,t) row ----------------
__global__ __launch_bounds__(64) void ln_kernel(const float* __restrict__ x,
    const float* __restrict__ w, const float* __restrict__ b, float* __restrict__ xn) {
  int row = blockIdx.x;           // b*L + t   (4096 rows)
  int lane = threadIdx.x;
  const float* xr = x + (size_t)row * HDIM;
  float4 v0 = ((const float4*)xr)[lane];
  float4 v1 = ((const float4*)xr)[lane + 64];
  float s  = v0.x + v0.y + v0.z + v0.w + v1.x + v1.y + v1.z + v1.w;
  float ss = v0.x*v0.x + v0.y*v0.y + v0.z*v0.z + v0.w*v0.w
           + v1.x*v1.x + v1.y*v1.y + v1.z*v1.z + v1.w*v1.w;
  #pragma unroll
  for (int m = 1; m < 64; m <<= 1) { s += __shfl_xor(s, m); ss += __shfl_xor(ss, m); }
  float mu   = s * (1.0f / HDIM);
  float var  = ss * (1.0f / HDIM) - mu * mu;
  float rstd = rsqrtf(var + 1e-5f);
  float4 w0 = ((const float4*)w)[lane];
  float4 w1 = ((const float4*)w)[lane + 64];
  float4 b0 = ((const float4*)b)[lane];
  float4 b1 = ((const float4*)b)[lane + 64];
  float4 o0, o1;
  o0.x = (v0.x - mu) * rstd * w0.x + b0.x;
  o0.y = (v0.y - mu) * rstd * w0.y + b0.y;
  o0.z = (v0.z - mu) * rstd * w0.z + b0.z;
  o0.w = (v0.w - mu) * rstd * w0.w + b0.w;
  o1.x = (v1.x - mu) * rstd * w1.x + b1.x;
  o1.y = (v1.y - mu) * rstd * w1.y + b1.y;
  o1.z = (v1.z - mu) * rstd * w1.z + b1.z;
  o1.w = (v1.w - mu) * rstd * w1.w + b1.w;
  float* xo = xn + (size_t)row * HDIM;
  ((float4*)xo)[lane] = o0;
  ((float4*)xo)[lane + 64] = o1;
}

// ---------------- K generation: setup + Ab^32 + chains + dots, ONE block ----------------
// K[32a+b] = Re( (c^T (Ab^32)^a) . (Ab^b Bb) ),  a,b in 0..31
__global__ __launch_bounds__(512) void kgen_kernel(
    const float* __restrict__ lre, const float* __restrict__ lim,
    const float* __restrict__ pre, const float* __restrict__ pim,
    const float* __restrict__ bre, const float* __restrict__ bim,
    const float* __restrict__ cre, const float* __restrict__ cim,
    const float* __restrict__ logstep, float* __restrict__ Kout) {
  __shared__ float2 M[4096];      // 64x64 complex, row-major: Ab then Ab^32
  __shared__ float2 Wv[2048];     // [n*32+b] = (Ab^b Bb)[n]
  __shared__ float2 Rv[2048];     // [n*32+a] = (c^T (Ab^32)^a)[n]
  __shared__ float2 Ldab[64], Lu[64], Lr[64], LBb[64];
  int tid = threadIdx.x;

  // --- Phase A: DPLR setup (wave 0, lane n = mode n) ---
  if (tid < 64) {
    int n = tid;
    float step = expf(logstep[0]);
    float g = 2.0f / step;
    float lr = lre[n], li = lim[n];
    float pr = pre[n], pi = pim[n];
    float br = bre[n], bi = bim[n];
    float den  = (g - lr) * (g - lr) + li * li;
    float dinr = (g - lr) / den, dini = li / den;
    float dabr = (g + lr) * dinr - li * dini;
    float dabi = (g + lr) * dini + li * dinr;
    float ur = dinr * pr - dini * pi;
    float ui = dinr * pi + dini * pr;
    float qr = pr * dinr + pi * dini;
    float qi = pr * dini - pi * dinr;
    float pm2 = pr * pr + pi * pi;
    float betr = pm2 * dinr, beti = pm2 * dini;
    float gar = qr * br - qi * bi;
    float gai = qr * bi + qi * br;
    #pragma unroll
    for (int m = 1; m < 64; m <<= 1) {
      betr += __shfl_xor(betr, m); beti += __shfl_xor(beti, m);
      gar  += __shfl_xor(gar, m);  gai  += __shfl_xor(gai, m);
    }
    float obr = 1.0f + betr, obi = beti;
    float ob2 = obr * obr + obi * obi;
    float kr = -2.0f * g * obr / ob2;
    float ki =  2.0f * g * obi / ob2;
    float rr = kr * qr - ki * qi;
    float ri = kr * qi + ki * qr;
    float tgr = (gar * obr + gai * obi) / ob2;
    float tgi = (gai * obr - gar * obi) / ob2;
    float dbr = dinr * br - dini * bi;
    float dbi = dinr * bi + dini * br;
    float Bbr = 2.0f * (dbr - (ur * tgr - ui * tgi));
    float Bbi = 2.0f * (dbi - (ur * tgi + ui * tgr));
    float2 t;
    t.x = dabr; t.y = dabi; Ldab[n] = t;
    t.x = ur;   t.y = ui;   Lu[n]   = t;
    t.x = rr;   t.y = ri;   Lr[n]   = t;
    t.x = Bbr;  t.y = Bbi;  LBb[n]  = t;
  }
  __syncthreads();

  // --- Phase B: build dense Ab[i][j] = u_i*r_j + delta_ij*dab_i ---
  #pragma unroll
  for (int q = 0; q < 8; q++) {
    int e = q * 512 + tid;
    int i = e >> 6, j = e & 63;
    float2 u = Lu[i], r = Lr[j];
    float2 v;
    v.x = u.x * r.x - u.y * r.y;
    v.y = u.x * r.y + u.y * r.x;
    if (i == j) { float2 dd = Ldab[i]; v.x += dd.x; v.y += dd.y; }
    M[e] = v;
  }
  __syncthreads();

  // --- Phase C: 5 in-place squarings -> M = Ab^32 ---
  // thread: col j = tid&63 (vector dim), rows i0..i0+7 = (tid>>6)*8
  {
    int j = tid & 63;
    int i0 = (tid >> 6) * 8;
    for (int sq = 0; sq < 5; sq++) {
      float2 o[8];
      #pragma unroll
      for (int ii = 0; ii < 8; ii++) { o[ii].x = 0.f; o[ii].y = 0.f; }
      for (int k = 0; k < 64; k++) {
        float2 bkj = M[k * 64 + j];          // vector read, conflict-free
        #pragma unroll
        for (int ii = 0; ii < 8; ii++) {
          float2 a = M[(i0 + ii) * 64 + k];  // wave-uniform broadcast
          o[ii].x += a.x * bkj.x - a.y * bkj.y;
          o[ii].y += a.x * bkj.y + a.y * bkj.x;
        }
      }
      __syncthreads();
      #pragma unroll
      for (int ii = 0; ii < 8; ii++) M[(i0 + ii) * 64 + j] = o[ii];
      __syncthreads();
    }
  }

  // --- Phase D: wave 0 = W chain (DPLR O(N) steps); wave 1 = R chain (dense matvec) ---
  if (tid < 64) {
    int n = tid;
    float2 dab = Ldab[n], u = Lu[n], r = Lr[n];
    float2 w = LBb[n];
    Wv[n * 32 + 0] = w;
    for (int b = 1; b < 32; b++) {
      float dr = r.x * w.x - r.y * w.y;
      float di = r.x * w.y + r.y * w.x;
      #pragma unroll
      for (int m = 1; m < 64; m <<= 1) { dr += __shfl_xor(dr, m); di += __shfl_xor(di, m); }
      float2 nw;
      nw.x = dab.x * w.x - dab.y * w.y + u.x * dr - u.y * di;
      nw.y = dab.x * w.y + dab.y * w.x + u.x * di + u.y * dr;
      w = nw;
      Wv[n * 32 + b] = w;
    }
  } else if (tid < 128) {
    int m = tid - 64;
    float2 c0; c0.x = cre[m]; c0.y = cim[m];
    Rv[m * 32 + 0] = c0;
    for (int a = 1; a < 32; a++) {
      float2 acc; acc.x = 0.f; acc.y = 0.f;
      for (int k = 0; k < 64; k++) {
        float2 rp = Rv[k * 32 + (a - 1)];    // uniform broadcast (same-wave DS order)
        float2 mm = M[k * 64 + m];           // vector read
        acc.x += rp.x * mm.x - rp.y * mm.y;
        acc.y += rp.x * mm.y + rp.y * mm.x;
      }
      Rv[m * 32 + a] = acc;
    }
  }
  __syncthreads();

  // --- Phase E: K[32a+b] = Re(R_a . W_b), 2 outputs per thread ---
  #pragma unroll
  for (int q = 0; q < 2; q++) {
    int midx = q * 512 + tid;
    int a = midx >> 5, b = midx & 31;
    float acc = 0.f;
    for (int n = 0; n < 64; n++) {
      float2 R = Rv[n * 32 + a];
      float2 W = Wv[n * 32 + b];
      acc += R.x * W.x - R.y * W.y;
    }
    Kout[midx] = acc;
  }
}

// ---------------- Toeplitz build: T[t][tau] = K[t-tau] (hi/lo bf16 split) ----------------
__global__ __launch_bounds__(256) void toeplitz_kernel(const float* __restrict__ K,
    ushort* __restrict__ Thi, ushort* __restrict__ Tlo) {
  int t = blockIdx.x;
  int tau0 = threadIdx.x * 4;
  ushort4 hi, lo;
  ushort* hp = (ushort*)&hi; ushort* lp = (ushort*)&lo;
  #pragma unroll
  for (int i = 0; i < 4; i++) {
    int tau = tau0 + i;
    float v = (tau <= t) ? K[t - tau] : 0.f;
    __hip_bfloat16 h = __float2bfloat16(v);
    float rem = v - __bfloat162float(h);
    __hip_bfloat16 l = __float2bfloat16(rem);
    hp[i] = *(ushort*)&h; lp[i] = *(ushort*)&l;
  }
  *(ushort4*)&Thi[(size_t)t * 1024 + tau0] = hi;
  *(ushort4*)&Tlo[(size_t)t * 1024 + tau0] = lo;
}

// ---------------- Transpose xn [B,L,H] -> U[c=b*512+h][t] (hi/lo bf16) ----------------
__global__ __launch_bounds__(256) void transpose_kernel(const float* __restrict__ xn,
    ushort* __restrict__ Uhi, ushort* __restrict__ Ulo) {
  __shared__ float tile[64][65];
  int ht = blockIdx.x;   // h tile (8)
  int lt = blockIdx.y;   // l tile (16)
  int b  = blockIdx.z;
  int tid = threadIdx.x;
  #pragma unroll
  for (int q = 0; q < 16; q++) {
    int idx = q * 256 + tid;
    int r = idx >> 6, c = idx & 63;                 // r: l-offset, c: h-offset
    tile[r][c] = xn[((size_t)(b * LSEQ + lt * 64 + r)) * HDIM + ht * 64 + c];
  }
  __syncthreads();
  #pragma unroll
  for (int q = 0; q < 16; q++) {
    int idx = q * 256 + tid;
    int r = idx >> 6, c = idx & 63;                 // r: h-offset, c: l-offset
    float v = tile[c][r];
    __hip_bfloat16 h = __float2bfloat16(v);
    float rem = v - __bfloat162float(h);
    __hip_bfloat16 l = __float2bfloat16(rem);
    size_t off = ((size_t)(b * HDIM + ht * 64 + r)) * LSEQ + lt * 64 + c;
    Uhi[off] = *(ushort*)&h;
    Ulo[off] = *(ushort*)&l;
  }
}

// -------- Conv GEMM: Y[1024x2048] = Thi*Uhi + Tlo*Uhi + Thi*Ulo (K=3x1024) --------
__global__ __launch_bounds__(256) void conv_gemm_kernel(
    const ushort* __restrict__ Thi, const ushort* __restrict__ Tlo,
    const ushort* __restrict__ Uhi, const ushort* __restrict__ Ulo,
    float* __restrict__ Y) {
  __shared__ ushort sA[128 * 32];
  __shared__ ushort sB[128 * 32];
  int tid = threadIdx.x;
  int lane = tid & 63;
  int wv = tid >> 6;
  int wm = wv >> 1, wn = wv & 1;
  int bm = blockIdx.y, bn = blockIdx.x;   // bm<8 (t), bn<16 (c)
  floatx4 acc[4][4] = {};
  int lrow = tid >> 2;
  int lcol = (tid & 3) * 8;
  int fr = lane & 15, fq = (lane >> 4) * 8;
  for (int kt = 0; kt < 96; kt++) {
    int region = kt >> 5;
    int k0 = (kt & 31) * 32;
    const ushort* Ag = ((region == 1) ? Tlo : Thi) + (size_t)(bm * 128) * 1024;
    const ushort* Bg = ((region == 2) ? Ulo : Uhi) + (size_t)(bn * 128) * 1024;
    #pragma unroll
    for (int q = 0; q < 2; q++) {
      int row = lrow + q * 64;
      *(uint4*)&sA[row * 32 + lcol] = *(const uint4*)&Ag[(size_t)row * 1024 + k0 + lcol];
      *(uint4*)&sB[row * 32 + lcol] = *(const uint4*)&Bg[(size_t)row * 1024 + k0 + lcol];
    }
    __syncthreads();
    short8 af[4], bf[4];
    #pragma unroll
    for (int i = 0; i < 4; i++) {
      af[i] = *(const short8*)&sA[(wm * 64 + i * 16 + fr) * 32 + fq];
      bf[i] = *(const short8*)&sB[(wn * 64 + i * 16 + fr) * 32 + fq];
    }
    #pragma unroll
    for (int i = 0; i < 4; i++)
      #pragma unroll
      for (int j = 0; j < 4; j++)
        acc[i][j] = __builtin_amdgcn_mfma_f32_16x16x32_bf16(af[i], bf[j], acc[i][j], 0, 0, 0);
    __syncthreads();
  }
  int row0 = bm * 128 + wm * 64;
  int col0 = bn * 128 + wn * 64;
  int fc = lane & 15, frq = (lane >> 4) * 4;
  #pragma unroll
  for (int i = 0; i < 4; i++)
    #pragma unroll
    for (int j = 0; j < 4; j++)
      #pragma unroll
      for (int r = 0; r < 4; r++)
        Y[(size_t)(row0 + i * 16 + frq + r) * 2048 + col0 + j * 16 + fc] = acc[i][j][r];
}

// ---------------- A-prep (elementwise): A[b,t,h] = gelu(Y[t][b*512+h] + d*xn) ----------------
__global__ __launch_bounds__(256) void aprep_kernel(const float* __restrict__ Y,
    const float* __restrict__ xn, const float* __restrict__ dptr,
    __hip_bfloat16* __restrict__ A) {
  int idx = blockIdx.x * 256 + threadIdx.x;       // 2M
  int h = idx & 511;
  int t = (idx >> 9) & 1023;
  int b = idx >> 19;
  float y = Y[(size_t)t * 2048 + b * 512 + h] + dptr[0] * xn[idx];
  float tnh = tanhf(0.7978845608028654f * (y + 0.044715f * y * y * y));
  float gl = 0.5f * y * (1.0f + tnh);
  A[idx] = __float2bfloat16(gl);
}

// ---------------- Weight convert/stack: Wst[1024][512] bf16 ----------------
__global__ __launch_bounds__(256) void wconv_kernel(const float* __restrict__ w1,
    const float* __restrict__ w2, __hip_bfloat16* __restrict__ Wst) {
  int idx = blockIdx.x * 256 + threadIdx.x;       // 524288
  int n = idx >> 9, k = idx & 511;
  float v = (n < 512) ? w1[n * 512 + k] : w2[(n - 512) * 512 + k];
  Wst[idx] = __float2bfloat16(v);
}

// ---------------- Proj GEMM: C[4096,1024] = A[4096,512] * Wst[1024,512]^T ----------------
__global__ __launch_bounds__(256) void gemm_kernel(const __hip_bfloat16* __restrict__ Abf,
    const __hip_bfloat16* __restrict__ Wst, float* __restrict__ C) {
  __shared__ unsigned short sA[128 * 32];
  __shared__ unsigned short sB[128 * 32];
  int tid = threadIdx.x;
  int lane = tid & 63;
  int wv = tid >> 6;
  int wm = wv >> 1, wn = wv & 1;
  int bm = blockIdx.y, bn = blockIdx.x;
  floatx4 acc[4][4] = {};
  const unsigned short* Ag = (const unsigned short*)Abf + (size_t)(bm * 128) * 512;
  const unsigned short* Bg = (const unsigned short*)Wst + (size_t)(bn * 128) * 512;
  int lrow = tid >> 2;
  int lcol = (tid & 3) * 8;
  int fr = lane & 15, fq = (lane >> 4) * 8;
  for (int kt = 0; kt < 16; kt++) {
    int k0 = kt * 32;
    #pragma unroll
    for (int q = 0; q < 2; q++) {
      int row = lrow + q * 64;
      *(uint4*)&sA[row * 32 + lcol] = *(const uint4*)&Ag[(size_t)row * 512 + k0 + lcol];
      *(uint4*)&sB[row * 32 + lcol] = *(const uint4*)&Bg[(size_t)row * 512 + k0 + lcol];
    }
    __syncthreads();
    short8 af[4], bf[4];
    #pragma unroll
    for (int i = 0; i < 4; i++) {
      af[i] = *(const short8*)&sA[(wm * 64 + i * 16 + fr) * 32 + fq];
      bf[i] = *(const short8*)&sB[(wn * 64 + i * 16 + fr) * 32 + fq];
    }
    #pragma unroll
    for (int i = 0; i < 4; i++)
      #pragma unroll
      for (int j = 0; j < 4; j++)
        acc[i][j] = __builtin_amdgcn_mfma_f32_16x16x32_bf16(af[i], bf[j], acc[i][j], 0, 0, 0);
    __syncthreads();
  }
  int row0 = bm * 128 + wm * 64;
  int col0 = bn * 128 + wn * 64;
  int fc = lane & 15, frq = (lane >> 4) * 4;
  #pragma unroll
  for (int i = 0; i < 4; i++)
    #pragma unroll
    for (int j = 0; j < 4; j++)
      #pragma unroll
      for (int r = 0; r < 4; r++)
        C[(size_t)(row0 + i * 16 + frq + r) * 1024 + col0 + j * 16 + fc] = acc[i][j][r];
}

// ---------------- Final: out = x + (C1 + ob) * sigmoid(C2 + o2b) ----------------
__global__ __launch_bounds__(256) void final_kernel(const float* __restrict__ x,
    const float* __restrict__ C, const float* __restrict__ ob,
    const float* __restrict__ o2b, float* __restrict__ out) {
  int idx = blockIdx.x * 256 + threadIdx.x;
  int i = idx & 511;
  int bt = idx >> 9;
  float c1 = C[(size_t)bt * 1024 + i] + ob[i];
  float c2 = C[(size_t)bt * 1024 + 512 + i] + o2b[i];
  float gate = 1.0f / (1.0f + expf(-c2));
  out[idx] = x[idx] + c1 * gate;
}

extern "C" void kernel_launch(void* const* d_in, const int* in_sizes, int n_in,
                              void* d_out, int out_size, void* d_ws, size_t ws_size,
                              hipStream_t stream) {
  const float* x   = (const float*)d_in[0];
  const float* nw  = (const float*)d_in[1];
  const float* nb  = (const float*)d_in[2];
  const float* lre = (const float*)d_in[3];
  const float* lim = (const float*)d_in[4];
  const float* pre = (const float*)d_in[5];
  const float* pim = (const float*)d_in[6];
  const float* bre = (const float*)d_in[7];
  const float* bim = (const float*)d_in[8];
  const float* cre = (const float*)d_in[9];
  const float* cim = (const float*)d_in[10];
  const float* dsc = (const float*)d_in[11];
  const float* lst = (const float*)d_in[12];
  const float* w1  = (const float*)d_in[13];
  const float* ob  = (const float*)d_in[14];
  const float* w2  = (const float*)d_in[15];
  const float* o2b = (const float*)d_in[16];

  char* ws = (char*)d_ws;
  // Layout (32 MB total, time-multiplexed):
  float* xn   = (float*)(ws);                              // 0..8MB   (live: ln..aprep)
  float* Yc   = (float*)(ws + (size_t)(8  << 20));         // 8..16MB  (conv out; live conv..aprep)
  float* Kbuf = (float*)(ws + (size_t)(8  << 20) + 65536); // K[1024] (consumed by toeplitz before conv writes Yc)
  ushort* Uhi = (ushort*)(ws + (size_t)(16 << 20));        // 16..20MB
  ushort* Ulo = (ushort*)(ws + (size_t)(20 << 20));        // 20..24MB
  ushort* Thi = (ushort*)(ws + (size_t)(24 << 20));        // 24..26MB
  ushort* Tlo = (ushort*)(ws + (size_t)(26 << 20));        // 26..28MB
  __hip_bfloat16* Abuf = (__hip_bfloat16*)(ws + (size_t)(28 << 20)); // 28..32MB
  __hip_bfloat16* Wst  = (__hip_bfloat16*)(ws + (size_t)(24 << 20)); // reuses Thi (after conv)
  float* C    = (float*)(ws + (size_t)(8 << 20));          // 8..24MB (after aprep)
  float* out  = (float*)d_out;

  ln_kernel<<<dim3(4096), dim3(64), 0, stream>>>(x, nw, nb, xn);
  kgen_kernel<<<dim3(1), dim3(512), 0, stream>>>(lre, lim, pre, pim, bre, bim,
                                                 cre, cim, lst, Kbuf);
  toeplitz_kernel<<<dim3(1024), dim3(256), 0, stream>>>(Kbuf, Thi, Tlo);
  transpose_kernel<<<dim3(8, 16, 4), dim3(256), 0, stream>>>(xn, Uhi, Ulo);
  conv_gemm_kernel<<<dim3(16, 8), dim3(256), 0, stream>>>(Thi, Tlo, Uhi, Ulo, Yc);
  wconv_kernel<<<dim3(2048), dim3(256), 0, stream>>>(w1, w2, Wst);
  aprep_kernel<<<dim3(8192), dim3(256), 0, stream>>>(Yc, xn, dsc, Abuf);
  gemm_kernel<<<dim3(8, 32), dim3(256), 0, stream>>>(Abuf, Wst, C);
  final_kernel<<<dim3(8192), dim3(256), 0, stream>>>(x, C, ob, o2b, out);
}

// Round 4
// 236.448 us; speedup vs baseline: 2.9038x; 1.3055x over previous
//
#include <hip/hip_runtime.h>
#include <hip/hip_bf16.h>
#include <math.h>

#define HDIM 512
#define LSEQ 1024
#define BSZ  4

typedef __attribute__((ext_vector_type(8))) short short8;
typedef __attribute__((ext_vector_type(4))) float floatx4;

__device__ __forceinline__ float2 cmul(float2 a, float2 b) {
  float2 r;
  r.x = a.x * b.x - a.y * b.y;
  r.y = a.x * b.y + a.y * b.x;
  return r;
}
__device__ __forceinline__ float2 cadd(float2 a, float2 b) {
  float2 r; r.x = a.x + b.x; r.y = a.y + b.y; return r;
}
__device__ __forceinline__ float2 cfma(float2 a, float2 b, float2 c) {
  // c += a*b
  c.x += a.x * b.x - a.y * b.y;
  c.y += a.x * b.y + a.y * b.x;
  return c;
}

// ---------------- LayerNorm: one wave per (b,t) row ----------------
__global__ __launch_bounds__(64) void ln_kernel(const float* __restrict__ x,
    const float* __restrict__ w, const float* __restrict__ b, float* __restrict__ xn) {
  int row = blockIdx.x;           // b*L + t   (4096 rows)
  int lane = threadIdx.x;
  const float* xr = x + (size_t)row * HDIM;
  float4 v0 = ((const float4*)xr)[lane];
  float4 v1 = ((const float4*)xr)[lane + 64];
  float s  = v0.x + v0.y + v0.z + v0.w + v1.x + v1.y + v1.z + v1.w;
  float ss = v0.x*v0.x + v0.y*v0.y + v0.z*v0.z + v0.w*v0.w
           + v1.x*v1.x + v1.y*v1.y + v1.z*v1.z + v1.w*v1.w;
  #pragma unroll
  for (int m = 1; m < 64; m <<= 1) { s += __shfl_xor(s, m); ss += __shfl_xor(ss, m); }
  float mu   = s * (1.0f / HDIM);
  float var  = ss * (1.0f / HDIM) - mu * mu;
  float rstd = rsqrtf(var + 1e-5f);
  float4 w0 = ((const float4*)w)[lane];
  float4 w1 = ((const float4*)w)[lane + 64];
  float4 b0 = ((const float4*)b)[lane];
  float4 b1 = ((const float4*)b)[lane + 64];
  float4 o0, o1;
  o0.x = (v0.x - mu) * rstd * w0.x + b0.x;
  o0.y = (v0.y - mu) * rstd * w0.y + b0.y;
  o0.z = (v0.z - mu) * rstd * w0.z + b0.z;
  o0.w = (v0.w - mu) * rstd * w0.w + b0.w;
  o1.x = (v1.x - mu) * rstd * w1.x + b1.x;
  o1.y = (v1.y - mu) * rstd * w1.y + b1.y;
  o1.z = (v1.z - mu) * rstd * w1.z + b1.z;
  o1.w = (v1.w - mu) * rstd * w1.w + b1.w;
  float* xo = xn + (size_t)row * HDIM;
  ((float4*)xo)[lane] = o0;
  ((float4*)xo)[lane + 64] = o1;
}

// ---------------- K generation (no dense squarings) ----------------
// K[32a+b] = Re( (c^T (Ab^32)^a) . (Ab^b Bb) )
// Ab^32 columns via 64 independent register-resident DPLR chains.
__global__ __launch_bounds__(512) void kgen_kernel(
    const float* __restrict__ lre, const float* __restrict__ lim,
    const float* __restrict__ pre, const float* __restrict__ pim,
    const float* __restrict__ bre, const float* __restrict__ bim,
    const float* __restrict__ cre, const float* __restrict__ cim,
    const float* __restrict__ logstep, float* __restrict__ Kout) {
  __shared__ float2 Ldab[64], Lu[64], Lr[64], LBb[64];
  __shared__ float2 P[8][64];     // partial dots
  __shared__ float2 M32[4096];    // Ab^32 row-major [i][j]
  __shared__ float2 Rv[2048];     // [a*64+n] = (c^T (Ab^32)^a)[n]
  __shared__ float2 Wv[2048];     // [n*32+b] = (Ab^b Bb)[n]
  int tid = threadIdx.x;
  int j = tid & 63;       // column (phase B) / output index m (phase C)
  int p = tid >> 6;       // partial group: rows p*8..p*8+7

  // --- Phase A: DPLR setup (wave 0, lane n = mode n) ---
  if (tid < 64) {
    int n = tid;
    float step = expf(logstep[0]);
    float g = 2.0f / step;
    float lr = lre[n], li = lim[n];
    float pr = pre[n], pi = pim[n];
    float br = bre[n], bi = bim[n];
    float den  = (g - lr) * (g - lr) + li * li;
    float dinr = (g - lr) / den, dini = li / den;
    float dabr = (g + lr) * dinr - li * dini;
    float dabi = (g + lr) * dini + li * dinr;
    float ur = dinr * pr - dini * pi;
    float ui = dinr * pi + dini * pr;
    float qr = pr * dinr + pi * dini;
    float qi = pr * dini - pi * dinr;
    float pm2 = pr * pr + pi * pi;
    float betr = pm2 * dinr, beti = pm2 * dini;
    float gar = qr * br - qi * bi;
    float gai = qr * bi + qi * br;
    #pragma unroll
    for (int m = 1; m < 64; m <<= 1) {
      betr += __shfl_xor(betr, m); beti += __shfl_xor(beti, m);
      gar  += __shfl_xor(gar, m);  gai  += __shfl_xor(gai, m);
    }
    float obr = 1.0f + betr, obi = beti;
    float ob2 = obr * obr + obi * obi;
    float kr = -2.0f * g * obr / ob2;
    float ki =  2.0f * g * obi / ob2;
    float rr = kr * qr - ki * qi;
    float ri = kr * qi + ki * qr;
    float tgr = (gar * obr + gai * obi) / ob2;
    float tgi = (gai * obr - gar * obi) / ob2;
    float dbr = dinr * br - dini * bi;
    float dbi = dinr * bi + dini * br;
    float Bbr = 2.0f * (dbr - (ur * tgr - ui * tgi));
    float Bbi = 2.0f * (dbi - (ur * tgi + ui * tgr));
    float2 t;
    t.x = dabr; t.y = dabi; Ldab[n] = t;
    t.x = ur;   t.y = ui;   Lu[n]   = t;
    t.x = rr;   t.y = ri;   Lr[n]   = t;
    t.x = Bbr;  t.y = Bbi;  LBb[n]  = t;
  }
  __syncthreads();

  // --- Phase B: 64 column chains, 32 applications of Ab (DPLR form) ---
  // Thread (j,p) holds rows n=p*8+ii of column j in registers.
  float2 dab[8], u[8], rn[8], cv[8];
  #pragma unroll
  for (int ii = 0; ii < 8; ii++) {
    int n = p * 8 + ii;
    dab[ii] = Ldab[n]; u[ii] = Lu[n]; rn[ii] = Lr[n];
  }
  float2 rj = Lr[j];
  #pragma unroll
  for (int ii = 0; ii < 8; ii++) {
    int n = p * 8 + ii;
    cv[ii] = cmul(u[ii], rj);                       // Ab = u r^T + diag(dab)
    if (n == j) cv[ii] = cadd(cv[ii], dab[ii]);     // application #1: Ab e_j
  }
  for (int s = 0; s < 31; s++) {                    // applications #2..#32
    float2 part; part.x = 0.f; part.y = 0.f;
    #pragma unroll
    for (int ii = 0; ii < 8; ii++) part = cfma(rn[ii], cv[ii], part);
    P[p][j] = part;
    __syncthreads();
    float2 d; d.x = 0.f; d.y = 0.f;
    #pragma unroll
    for (int q = 0; q < 8; q++) d = cadd(d, P[q][j]);
    __syncthreads();
    #pragma unroll
    for (int ii = 0; ii < 8; ii++) {
      float2 nc = cmul(dab[ii], cv[ii]);
      nc = cfma(u[ii], d, nc);
      cv[ii] = nc;
    }
  }
  // write M32[i][j] = (Ab^32)_{ij}
  #pragma unroll
  for (int ii = 0; ii < 8; ii++) M32[(p * 8 + ii) * 64 + j] = cv[ii];
  if (tid < 64) { float2 cc; cc.x = cre[tid]; cc.y = cim[tid]; Rv[tid] = cc; }
  __syncthreads();

  // --- Phase C: R chain, R_a = R_{a-1} * Ab^32, parallel partials ---
  // Thread (m=j, p): partial over k = p*8+ii, M-strip preloaded to registers.
  float2 Mreg[8];
  #pragma unroll
  for (int ii = 0; ii < 8; ii++) Mreg[ii] = M32[(p * 8 + ii) * 64 + j];
  for (int a = 1; a < 32; a++) {
    float2 part; part.x = 0.f; part.y = 0.f;
    #pragma unroll
    for (int ii = 0; ii < 8; ii++) {
      float2 Rk = Rv[(a - 1) * 64 + p * 8 + ii];    // wave-uniform broadcast
      part = cfma(Rk, Mreg[ii], part);
    }
    P[p][j] = part;
    __syncthreads();
    if (p == 0) {
      float2 d; d.x = 0.f; d.y = 0.f;
      #pragma unroll
      for (int q = 0; q < 8; q++) d = cadd(d, P[q][j]);
      Rv[a * 64 + j] = d;
    }
    __syncthreads();
  }

  // --- Phase D: W chain (wave 0, DPLR O(N) with butterflies, 31 steps) ---
  if (tid < 64) {
    int n = tid;
    float2 dab0 = Ldab[n], u0 = Lu[n], r0 = Lr[n];
    float2 w = LBb[n];
    Wv[n * 32 + 0] = w;
    for (int b = 1; b < 32; b++) {
      float dr = r0.x * w.x - r0.y * w.y;
      float di = r0.x * w.y + r0.y * w.x;
      #pragma unroll
      for (int m = 1; m < 64; m <<= 1) { dr += __shfl_xor(dr, m); di += __shfl_xor(di, m); }
      float2 nw;
      nw.x = dab0.x * w.x - dab0.y * w.y + u0.x * dr - u0.y * di;
      nw.y = dab0.x * w.y + dab0.y * w.x + u0.x * di + u0.y * dr;
      w = nw;
      Wv[n * 32 + b] = w;
    }
  }
  __syncthreads();

  // --- Phase E: K[32a+b] = Re(R_a . W_b), 2 outputs per thread ---
  #pragma unroll
  for (int q = 0; q < 2; q++) {
    int midx = q * 512 + tid;
    int a = midx >> 5, b = midx & 31;
    float acc = 0.f;
    for (int n = 0; n < 64; n++) {
      float2 R = Rv[a * 64 + n];     // broadcast within 32-thread groups
      float2 W = Wv[n * 32 + b];     // vector, contiguous in b
      acc += R.x * W.x - R.y * W.y;
    }
    Kout[midx] = acc;
  }
}

// ---------------- Toeplitz build: T[t][tau] = K[t-tau] (hi/lo bf16 split) ----------------
__global__ __launch_bounds__(256) void toeplitz_kernel(const float* __restrict__ K,
    ushort* __restrict__ Thi, ushort* __restrict__ Tlo) {
  int t = blockIdx.x;
  int tau0 = threadIdx.x * 4;
  ushort4 hi, lo;
  ushort* hp = (ushort*)&hi; ushort* lp = (ushort*)&lo;
  #pragma unroll
  for (int i = 0; i < 4; i++) {
    int tau = tau0 + i;
    float v = (tau <= t) ? K[t - tau] : 0.f;
    __hip_bfloat16 h = __float2bfloat16(v);
    float rem = v - __bfloat162float(h);
    __hip_bfloat16 l = __float2bfloat16(rem);
    hp[i] = *(ushort*)&h; lp[i] = *(ushort*)&l;
  }
  *(ushort4*)&Thi[(size_t)t * 1024 + tau0] = hi;
  *(ushort4*)&Tlo[(size_t)t * 1024 + tau0] = lo;
}

// ---------------- Transpose xn [B,L,H] -> U[c=b*512+h][t] (hi/lo bf16) ----------------
__global__ __launch_bounds__(256) void transpose_kernel(const float* __restrict__ xn,
    ushort* __restrict__ Uhi, ushort* __restrict__ Ulo) {
  __shared__ float tile[64][65];
  int ht = blockIdx.x;   // h tile (8)
  int lt = blockIdx.y;   // l tile (16)
  int b  = blockIdx.z;
  int tid = threadIdx.x;
  #pragma unroll
  for (int q = 0; q < 16; q++) {
    int idx = q * 256 + tid;
    int r = idx >> 6, c = idx & 63;                 // r: l-offset, c: h-offset
    tile[r][c] = xn[((size_t)(b * LSEQ + lt * 64 + r)) * HDIM + ht * 64 + c];
  }
  __syncthreads();
  #pragma unroll
  for (int q = 0; q < 16; q++) {
    int idx = q * 256 + tid;
    int r = idx >> 6, c = idx & 63;                 // r: h-offset, c: l-offset
    float v = tile[c][r];
    __hip_bfloat16 h = __float2bfloat16(v);
    float rem = v - __bfloat162float(h);
    __hip_bfloat16 l = __float2bfloat16(rem);
    size_t off = ((size_t)(b * HDIM + ht * 64 + r)) * LSEQ + lt * 64 + c;
    Uhi[off] = *(ushort*)&h;
    Ulo[off] = *(ushort*)&l;
  }
}

// -------- Conv GEMM: Y[1024x2048] = Thi*Uhi + Tlo*Uhi + Thi*Ulo (K=3x1024) --------
__global__ __launch_bounds__(256) void conv_gemm_kernel(
    const ushort* __restrict__ Thi, const ushort* __restrict__ Tlo,
    const ushort* __restrict__ Uhi, const ushort* __restrict__ Ulo,
    float* __restrict__ Y) {
  __shared__ ushort sA[128 * 32];
  __shared__ ushort sB[128 * 32];
  int tid = threadIdx.x;
  int lane = tid & 63;
  int wv = tid >> 6;
  int wm = wv >> 1, wn = wv & 1;
  int bm = blockIdx.y, bn = blockIdx.x;   // bm<8 (t), bn<16 (c)
  floatx4 acc[4][4] = {};
  int lrow = tid >> 2;
  int lcol = (tid & 3) * 8;
  int fr = lane & 15, fq = (lane >> 4) * 8;
  for (int kt = 0; kt < 96; kt++) {
    int region = kt >> 5;
    int k0 = (kt & 31) * 32;
    const ushort* Ag = ((region == 1) ? Tlo : Thi) + (size_t)(bm * 128) * 1024;
    const ushort* Bg = ((region == 2) ? Ulo : Uhi) + (size_t)(bn * 128) * 1024;
    #pragma unroll
    for (int q = 0; q < 2; q++) {
      int row = lrow + q * 64;
      *(uint4*)&sA[row * 32 + lcol] = *(const uint4*)&Ag[(size_t)row * 1024 + k0 + lcol];
      *(uint4*)&sB[row * 32 + lcol] = *(const uint4*)&Bg[(size_t)row * 1024 + k0 + lcol];
    }
    __syncthreads();
    short8 af[4], bf[4];
    #pragma unroll
    for (int i = 0; i < 4; i++) {
      af[i] = *(const short8*)&sA[(wm * 64 + i * 16 + fr) * 32 + fq];
      bf[i] = *(const short8*)&sB[(wn * 64 + i * 16 + fr) * 32 + fq];
    }
    #pragma unroll
    for (int i = 0; i < 4; i++)
      #pragma unroll
      for (int j = 0; j < 4; j++)
        acc[i][j] = __builtin_amdgcn_mfma_f32_16x16x32_bf16(af[i], bf[j], acc[i][j], 0, 0, 0);
    __syncthreads();
  }
  int row0 = bm * 128 + wm * 64;
  int col0 = bn * 128 + wn * 64;
  int fc = lane & 15, frq = (lane >> 4) * 4;
  #pragma unroll
  for (int i = 0; i < 4; i++)
    #pragma unroll
    for (int j = 0; j < 4; j++)
      #pragma unroll
      for (int r = 0; r < 4; r++)
        Y[(size_t)(row0 + i * 16 + frq + r) * 2048 + col0 + j * 16 + fc] = acc[i][j][r];
}

// ---------------- A-prep (elementwise): A[b,t,h] = gelu(Y[t][b*512+h] + d*xn) ----------------
__global__ __launch_bounds__(256) void aprep_kernel(const float* __restrict__ Y,
    const float* __restrict__ xn, const float* __restrict__ dptr,
    __hip_bfloat16* __restrict__ A) {
  int idx = blockIdx.x * 256 + threadIdx.x;       // 2M
  int h = idx & 511;
  int t = (idx >> 9) & 1023;
  int b = idx >> 19;
  float y = Y[(size_t)t * 2048 + b * 512 + h] + dptr[0] * xn[idx];
  float tnh = tanhf(0.7978845608028654f * (y + 0.044715f * y * y * y));
  float gl = 0.5f * y * (1.0f + tnh);
  A[idx] = __float2bfloat16(gl);
}

// ---------------- Weight convert/stack: Wst[1024][512] bf16 ----------------
__global__ __launch_bounds__(256) void wconv_kernel(const float* __restrict__ w1,
    const float* __restrict__ w2, __hip_bfloat16* __restrict__ Wst) {
  int idx = blockIdx.x * 256 + threadIdx.x;       // 524288
  int n = idx >> 9, k = idx & 511;
  float v = (n < 512) ? w1[n * 512 + k] : w2[(n - 512) * 512 + k];
  Wst[idx] = __float2bfloat16(v);
}

// ---------------- Proj GEMM: C[4096,1024] = A[4096,512] * Wst[1024,512]^T ----------------
__global__ __launch_bounds__(256) void gemm_kernel(const __hip_bfloat16* __restrict__ Abf,
    const __hip_bfloat16* __restrict__ Wst, float* __restrict__ C) {
  __shared__ unsigned short sA[128 * 32];
  __shared__ unsigned short sB[128 * 32];
  int tid = threadIdx.x;
  int lane = tid & 63;
  int wv = tid >> 6;
  int wm = wv >> 1, wn = wv & 1;
  int bm = blockIdx.y, bn = blockIdx.x;
  floatx4 acc[4][4] = {};
  const unsigned short* Ag = (const unsigned short*)Abf + (size_t)(bm * 128) * 512;
  const unsigned short* Bg = (const unsigned short*)Wst + (size_t)(bn * 128) * 512;
  int lrow = tid >> 2;
  int lcol = (tid & 3) * 8;
  int fr = lane & 15, fq = (lane >> 4) * 8;
  for (int kt = 0; kt < 16; kt++) {
    int k0 = kt * 32;
    #pragma unroll
    for (int q = 0; q < 2; q++) {
      int row = lrow + q * 64;
      *(uint4*)&sA[row * 32 + lcol] = *(const uint4*)&Ag[(size_t)row * 512 + k0 + lcol];
      *(uint4*)&sB[row * 32 + lcol] = *(const uint4*)&Bg[(size_t)row * 512 + k0 + lcol];
    }
    __syncthreads();
    short8 af[4], bf[4];
    #pragma unroll
    for (int i = 0; i < 4; i++) {
      af[i] = *(const short8*)&sA[(wm * 64 + i * 16 + fr) * 32 + fq];
      bf[i] = *(const short8*)&sB[(wn * 64 + i * 16 + fr) * 32 + fq];
    }
    #pragma unroll
    for (int i = 0; i < 4; i++)
      #pragma unroll
      for (int j = 0; j < 4; j++)
        acc[i][j] = __builtin_amdgcn_mfma_f32_16x16x32_bf16(af[i], bf[j], acc[i][j], 0, 0, 0);
    __syncthreads();
  }
  int row0 = bm * 128 + wm * 64;
  int col0 = bn * 128 + wn * 64;
  int fc = lane & 15, frq = (lane >> 4) * 4;
  #pragma unroll
  for (int i = 0; i < 4; i++)
    #pragma unroll
    for (int j = 0; j < 4; j++)
      #pragma unroll
      for (int r = 0; r < 4; r++)
        C[(size_t)(row0 + i * 16 + frq + r) * 1024 + col0 + j * 16 + fc] = acc[i][j][r];
}

// ---------------- Final: out = x + (C1 + ob) * sigmoid(C2 + o2b) ----------------
__global__ __launch_bounds__(256) void final_kernel(const float* __restrict__ x,
    const float* __restrict__ C, const float* __restrict__ ob,
    const float* __restrict__ o2b, float* __restrict__ out) {
  int idx = blockIdx.x * 256 + threadIdx.x;
  int i = idx & 511;
  int bt = idx >> 9;
  float c1 = C[(size_t)bt * 1024 + i] + ob[i];
  float c2 = C[(size_t)bt * 1024 + 512 + i] + o2b[i];
  float gate = 1.0f / (1.0f + expf(-c2));
  out[idx] = x[idx] + c1 * gate;
}

extern "C" void kernel_launch(void* const* d_in, const int* in_sizes, int n_in,
                              void* d_out, int out_size, void* d_ws, size_t ws_size,
                              hipStream_t stream) {
  const float* x   = (const float*)d_in[0];
  const float* nw  = (const float*)d_in[1];
  const float* nb  = (const float*)d_in[2];
  const float* lre = (const float*)d_in[3];
  const float* lim = (const float*)d_in[4];
  const float* pre = (const float*)d_in[5];
  const float* pim = (const float*)d_in[6];
  const float* bre = (const float*)d_in[7];
  const float* bim = (const float*)d_in[8];
  const float* cre = (const float*)d_in[9];
  const float* cim = (const float*)d_in[10];
  const float* dsc = (const float*)d_in[11];
  const float* lst = (const float*)d_in[12];
  const float* w1  = (const float*)d_in[13];
  const float* ob  = (const float*)d_in[14];
  const float* w2  = (const float*)d_in[15];
  const float* o2b = (const float*)d_in[16];

  char* ws = (char*)d_ws;
  // Layout (32 MB total, time-multiplexed):
  float* xn   = (float*)(ws);                              // 0..8MB   (live: ln..aprep)
  float* Yc   = (float*)(ws + (size_t)(8  << 20));         // 8..16MB  (conv out; live conv..aprep)
  float* Kbuf = (float*)(ws + (size_t)(8  << 20) + 65536); // K[1024] (consumed by toeplitz before conv writes Yc)
  ushort* Uhi = (ushort*)(ws + (size_t)(16 << 20));        // 16..20MB
  ushort* Ulo = (ushort*)(ws + (size_t)(20 << 20));        // 20..24MB
  ushort* Thi = (ushort*)(ws + (size_t)(24 << 20));        // 24..26MB
  ushort* Tlo = (ushort*)(ws + (size_t)(26 << 20));        // 26..28MB
  __hip_bfloat16* Abuf = (__hip_bfloat16*)(ws + (size_t)(28 << 20)); // 28..32MB
  __hip_bfloat16* Wst  = (__hip_bfloat16*)(ws + (size_t)(24 << 20)); // reuses Thi (after conv)
  float* C    = (float*)(ws + (size_t)(8 << 20));          // 8..24MB (after aprep)
  float* out  = (float*)d_out;

  ln_kernel<<<dim3(4096), dim3(64), 0, stream>>>(x, nw, nb, xn);
  kgen_kernel<<<dim3(1), dim3(512), 0, stream>>>(lre, lim, pre, pim, bre, bim,
                                                 cre, cim, lst, Kbuf);
  toeplitz_kernel<<<dim3(1024), dim3(256), 0, stream>>>(Kbuf, Thi, Tlo);
  transpose_kernel<<<dim3(8, 16, 4), dim3(256), 0, stream>>>(xn, Uhi, Ulo);
  conv_gemm_kernel<<<dim3(16, 8), dim3(256), 0, stream>>>(Thi, Tlo, Uhi, Ulo, Yc);
  wconv_kernel<<<dim3(2048), dim3(256), 0, stream>>>(w1, w2, Wst);
  aprep_kernel<<<dim3(8192), dim3(256), 0, stream>>>(Yc, xn, dsc, Abuf);
  gemm_kernel<<<dim3(8, 32), dim3(256), 0, stream>>>(Abuf, Wst, C);
  final_kernel<<<dim3(8192), dim3(256), 0, stream>>>(x, C, ob, o2b, out);
}

// Round 5
// 223.864 us; speedup vs baseline: 3.0670x; 1.0562x over previous
//
#include <hip/hip_runtime.h>
#include <hip/hip_bf16.h>
#include <math.h>

#define HDIM 512
#define LSEQ 1024
#define BSZ  4

typedef __attribute__((ext_vector_type(8))) short short8;
typedef __attribute__((ext_vector_type(4))) float floatx4;

__device__ __forceinline__ float2 cmul(float2 a, float2 b) {
  float2 r;
  r.x = a.x * b.x - a.y * b.y;
  r.y = a.x * b.y + a.y * b.x;
  return r;
}
__device__ __forceinline__ float2 cadd(float2 a, float2 b) {
  float2 r; r.x = a.x + b.x; r.y = a.y + b.y; return r;
}
__device__ __forceinline__ float2 cfma(float2 a, float2 b, float2 c) {
  c.x += a.x * b.x - a.y * b.y;
  c.y += a.x * b.y + a.y * b.x;
  return c;
}
__device__ __forceinline__ ushort f2bf(float f) {
  __hip_bfloat16 h = __float2bfloat16(f);
  return *(ushort*)&h;
}

// ---------------- LayerNorm: one wave per (b,t) row ----------------
__global__ __launch_bounds__(64) void ln_kernel(const float* __restrict__ x,
    const float* __restrict__ w, const float* __restrict__ b, float* __restrict__ xn) {
  int row = blockIdx.x;           // b*L + t   (4096 rows)
  int lane = threadIdx.x;
  const float* xr = x + (size_t)row * HDIM;
  float4 v0 = ((const float4*)xr)[lane];
  float4 v1 = ((const float4*)xr)[lane + 64];
  float s  = v0.x + v0.y + v0.z + v0.w + v1.x + v1.y + v1.z + v1.w;
  float ss = v0.x*v0.x + v0.y*v0.y + v0.z*v0.z + v0.w*v0.w
           + v1.x*v1.x + v1.y*v1.y + v1.z*v1.z + v1.w*v1.w;
  #pragma unroll
  for (int m = 1; m < 64; m <<= 1) { s += __shfl_xor(s, m); ss += __shfl_xor(ss, m); }
  float mu   = s * (1.0f / HDIM);
  float var  = ss * (1.0f / HDIM) - mu * mu;
  float rstd = rsqrtf(var + 1e-5f);
  float4 w0 = ((const float4*)w)[lane];
  float4 w1 = ((const float4*)w)[lane + 64];
  float4 b0 = ((const float4*)b)[lane];
  float4 b1 = ((const float4*)b)[lane + 64];
  float4 o0, o1;
  o0.x = (v0.x - mu) * rstd * w0.x + b0.x;
  o0.y = (v0.y - mu) * rstd * w0.y + b0.y;
  o0.z = (v0.z - mu) * rstd * w0.z + b0.z;
  o0.w = (v0.w - mu) * rstd * w0.w + b0.w;
  o1.x = (v1.x - mu) * rstd * w1.x + b1.x;
  o1.y = (v1.y - mu) * rstd * w1.y + b1.y;
  o1.z = (v1.z - mu) * rstd * w1.z + b1.z;
  o1.w = (v1.w - mu) * rstd * w1.w + b1.w;
  float* xo = xn + (size_t)row * HDIM;
  ((float4*)xo)[lane] = o0;
  ((float4*)xo)[lane + 64] = o1;
}

// ---------------- K generation (register-resident DPLR column chains) ----------------
// K[32a+b] = Re( (c^T (Ab^32)^a) . (Ab^b Bb) )
__global__ __launch_bounds__(512) void kgen_kernel(
    const float* __restrict__ lre, const float* __restrict__ lim,
    const float* __restrict__ pre, const float* __restrict__ pim,
    const float* __restrict__ bre, const float* __restrict__ bim,
    const float* __restrict__ cre, const float* __restrict__ cim,
    const float* __restrict__ logstep, float* __restrict__ Kout) {
  __shared__ float2 Ldab[64], Lu[64], Lr[64], LBb[64];
  __shared__ float2 P[8][64];     // partial dots
  __shared__ float2 M32[4096];    // Ab^32 row-major [i][j]
  __shared__ float2 Rv[2048];     // [a*64+n] = (c^T (Ab^32)^a)[n]
  __shared__ float2 Wv[2048];     // [n*32+b] = (Ab^b Bb)[n]
  int tid = threadIdx.x;
  int j = tid & 63;       // column (phase B) / output index m (phase C)
  int p = tid >> 6;       // partial group: rows p*8..p*8+7

  // --- Phase A: DPLR setup (wave 0, lane n = mode n) ---
  if (tid < 64) {
    int n = tid;
    float step = expf(logstep[0]);
    float g = 2.0f / step;
    float lr = lre[n], li = lim[n];
    float pr = pre[n], pi = pim[n];
    float br = bre[n], bi = bim[n];
    float den  = (g - lr) * (g - lr) + li * li;
    float dinr = (g - lr) / den, dini = li / den;
    float dabr = (g + lr) * dinr - li * dini;
    float dabi = (g + lr) * dini + li * dinr;
    float ur = dinr * pr - dini * pi;
    float ui = dinr * pi + dini * pr;
    float qr = pr * dinr + pi * dini;
    float qi = pr * dini - pi * dinr;
    float pm2 = pr * pr + pi * pi;
    float betr = pm2 * dinr, beti = pm2 * dini;
    float gar = qr * br - qi * bi;
    float gai = qr * bi + qi * br;
    #pragma unroll
    for (int m = 1; m < 64; m <<= 1) {
      betr += __shfl_xor(betr, m); beti += __shfl_xor(beti, m);
      gar  += __shfl_xor(gar, m);  gai  += __shfl_xor(gai, m);
    }
    float obr = 1.0f + betr, obi = beti;
    float ob2 = obr * obr + obi * obi;
    float kr = -2.0f * g * obr / ob2;
    float ki =  2.0f * g * obi / ob2;
    float rr = kr * qr - ki * qi;
    float ri = kr * qi + ki * qr;
    float tgr = (gar * obr + gai * obi) / ob2;
    float tgi = (gai * obr - gar * obi) / ob2;
    float dbr = dinr * br - dini * bi;
    float dbi = dinr * bi + dini * br;
    float Bbr = 2.0f * (dbr - (ur * tgr - ui * tgi));
    float Bbi = 2.0f * (dbi - (ur * tgi + ui * tgr));
    float2 t;
    t.x = dabr; t.y = dabi; Ldab[n] = t;
    t.x = ur;   t.y = ui;   Lu[n]   = t;
    t.x = rr;   t.y = ri;   Lr[n]   = t;
    t.x = Bbr;  t.y = Bbi;  LBb[n]  = t;
  }
  __syncthreads();

  // --- Phase B: 64 column chains, 32 applications of Ab (DPLR form) ---
  float2 dab[8], u[8], rn[8], cv[8];
  #pragma unroll
  for (int ii = 0; ii < 8; ii++) {
    int n = p * 8 + ii;
    dab[ii] = Ldab[n]; u[ii] = Lu[n]; rn[ii] = Lr[n];
  }
  float2 rj = Lr[j];
  #pragma unroll
  for (int ii = 0; ii < 8; ii++) {
    int n = p * 8 + ii;
    cv[ii] = cmul(u[ii], rj);
    if (n == j) cv[ii] = cadd(cv[ii], dab[ii]);
  }
  for (int s = 0; s < 31; s++) {
    float2 part; part.x = 0.f; part.y = 0.f;
    #pragma unroll
    for (int ii = 0; ii < 8; ii++) part = cfma(rn[ii], cv[ii], part);
    P[p][j] = part;
    __syncthreads();
    float2 d; d.x = 0.f; d.y = 0.f;
    #pragma unroll
    for (int q = 0; q < 8; q++) d = cadd(d, P[q][j]);
    __syncthreads();
    #pragma unroll
    for (int ii = 0; ii < 8; ii++) {
      float2 nc = cmul(dab[ii], cv[ii]);
      nc = cfma(u[ii], d, nc);
      cv[ii] = nc;
    }
  }
  #pragma unroll
  for (int ii = 0; ii < 8; ii++) M32[(p * 8 + ii) * 64 + j] = cv[ii];
  if (tid < 64) { float2 cc; cc.x = cre[tid]; cc.y = cim[tid]; Rv[tid] = cc; }
  __syncthreads();

  // --- Phase C: R chain, parallel partials with register M-strip ---
  float2 Mreg[8];
  #pragma unroll
  for (int ii = 0; ii < 8; ii++) Mreg[ii] = M32[(p * 8 + ii) * 64 + j];
  for (int a = 1; a < 32; a++) {
    float2 part; part.x = 0.f; part.y = 0.f;
    #pragma unroll
    for (int ii = 0; ii < 8; ii++) {
      float2 Rk = Rv[(a - 1) * 64 + p * 8 + ii];
      part = cfma(Rk, Mreg[ii], part);
    }
    P[p][j] = part;
    __syncthreads();
    if (p == 0) {
      float2 d; d.x = 0.f; d.y = 0.f;
      #pragma unroll
      for (int q = 0; q < 8; q++) d = cadd(d, P[q][j]);
      Rv[a * 64 + j] = d;
    }
    __syncthreads();
  }

  // --- Phase D: W chain (wave 0) ---
  if (tid < 64) {
    int n = tid;
    float2 dab0 = Ldab[n], u0 = Lu[n], r0 = Lr[n];
    float2 w = LBb[n];
    Wv[n * 32 + 0] = w;
    for (int b = 1; b < 32; b++) {
      float dr = r0.x * w.x - r0.y * w.y;
      float di = r0.x * w.y + r0.y * w.x;
      #pragma unroll
      for (int m = 1; m < 64; m <<= 1) { dr += __shfl_xor(dr, m); di += __shfl_xor(di, m); }
      float2 nw;
      nw.x = dab0.x * w.x - dab0.y * w.y + u0.x * dr - u0.y * di;
      nw.y = dab0.x * w.y + dab0.y * w.x + u0.x * di + u0.y * dr;
      w = nw;
      Wv[n * 32 + b] = w;
    }
  }
  __syncthreads();

  // --- Phase E: K[32a+b] = Re(R_a . W_b) ---
  #pragma unroll
  for (int q = 0; q < 2; q++) {
    int midx = q * 512 + tid;
    int a = midx >> 5, b = midx & 31;
    float acc = 0.f;
    for (int n = 0; n < 64; n++) {
      float2 R = Rv[a * 64 + n];
      float2 W = Wv[n * 32 + b];
      acc += R.x * W.x - R.y * W.y;
    }
    Kout[midx] = acc;
  }
}

// ---------------- Toeplitz build: T[t][tau] = K[t-tau] (hi/lo bf16 split) ----------------
__global__ __launch_bounds__(256) void toeplitz_kernel(const float* __restrict__ K,
    ushort* __restrict__ Thi, ushort* __restrict__ Tlo) {
  int t = blockIdx.x;
  int tau0 = threadIdx.x * 4;
  ushort4 hi, lo;
  ushort* hp = (ushort*)&hi; ushort* lp = (ushort*)&lo;
  #pragma unroll
  for (int i = 0; i < 4; i++) {
    int tau = tau0 + i;
    float v = (tau <= t) ? K[t - tau] : 0.f;
    __hip_bfloat16 h = __float2bfloat16(v);
    float rem = v - __bfloat162float(h);
    __hip_bfloat16 l = __float2bfloat16(rem);
    hp[i] = *(ushort*)&h; lp[i] = *(ushort*)&l;
  }
  *(ushort4*)&Thi[(size_t)t * 1024 + tau0] = hi;
  *(ushort4*)&Tlo[(size_t)t * 1024 + tau0] = lo;
}

// ---------------- Transpose xn [B,L,H] -> U[c=b*512+h][t] (hi/lo bf16) ----------------
__global__ __launch_bounds__(256) void transpose_kernel(const float* __restrict__ xn,
    ushort* __restrict__ Uhi, ushort* __restrict__ Ulo) {
  __shared__ float tile[64][65];
  int ht = blockIdx.x;   // h tile (8)
  int lt = blockIdx.y;   // l tile (16)
  int b  = blockIdx.z;
  int tid = threadIdx.x;
  #pragma unroll
  for (int q = 0; q < 16; q++) {
    int idx = q * 256 + tid;
    int r = idx >> 6, c = idx & 63;                 // r: l-offset, c: h-offset
    tile[r][c] = xn[((size_t)(b * LSEQ + lt * 64 + r)) * HDIM + ht * 64 + c];
  }
  __syncthreads();
  #pragma unroll
  for (int q = 0; q < 16; q++) {
    int idx = q * 256 + tid;
    int r = idx >> 6, c = idx & 63;                 // r: h-offset, c: l-offset
    float v = tile[c][r];
    __hip_bfloat16 h = __float2bfloat16(v);
    float rem = v - __bfloat162float(h);
    __hip_bfloat16 l = __float2bfloat16(rem);
    size_t off = ((size_t)(b * HDIM + ht * 64 + r)) * LSEQ + lt * 64 + c;
    Uhi[off] = *(ushort*)&h;
    Ulo[off] = *(ushort*)&l;
  }
}

// -------- Conv GEMM: Y[1024x2048] = Thi*Uhi + Tlo*Uhi + Thi*Ulo (K=3x1024) --------
// 64x64 tiles, 512 blocks (2/CU), padded LDS (stride 40 ushorts = 80B).
__global__ __launch_bounds__(256) void conv_gemm_kernel(
    const ushort* __restrict__ Thi, const ushort* __restrict__ Tlo,
    const ushort* __restrict__ Uhi, const ushort* __restrict__ Ulo,
    float* __restrict__ Y) {
  __shared__ ushort sA[64 * 40];
  __shared__ ushort sB[64 * 40];
  int tid = threadIdx.x;
  int lane = tid & 63;
  int wv = tid >> 6;
  int wm = wv >> 1, wn = wv & 1;
  int bm = blockIdx.y, bn = blockIdx.x;   // bm<16 (t tiles), bn<32 (c tiles)
  floatx4 acc[2][2] = {};
  int srow = tid >> 2;
  int scol = (tid & 3) * 8;
  int fr = lane & 15, fq = (lane >> 4) * 8;
  for (int kt = 0; kt < 96; kt++) {
    int region = kt >> 5;
    int k0 = (kt & 31) * 32;
    const ushort* Ag = ((region == 1) ? Tlo : Thi) + (size_t)(bm * 64) * 1024;
    const ushort* Bg = ((region == 2) ? Ulo : Uhi) + (size_t)(bn * 64) * 1024;
    *(uint4*)&sA[srow * 40 + scol] = *(const uint4*)&Ag[(size_t)srow * 1024 + k0 + scol];
    *(uint4*)&sB[srow * 40 + scol] = *(const uint4*)&Bg[(size_t)srow * 1024 + k0 + scol];
    __syncthreads();
    short8 af[2], bf[2];
    #pragma unroll
    for (int i = 0; i < 2; i++) {
      af[i] = *(const short8*)&sA[(wm * 32 + i * 16 + fr) * 40 + fq];
      bf[i] = *(const short8*)&sB[(wn * 32 + i * 16 + fr) * 40 + fq];
    }
    #pragma unroll
    for (int i = 0; i < 2; i++)
      #pragma unroll
      for (int j = 0; j < 2; j++)
        acc[i][j] = __builtin_amdgcn_mfma_f32_16x16x32_bf16(af[i], bf[j], acc[i][j], 0, 0, 0);
    __syncthreads();
  }
  int row0 = bm * 64 + wm * 32;
  int col0 = bn * 64 + wn * 32;
  int fc = lane & 15, frq = (lane >> 4) * 4;
  #pragma unroll
  for (int i = 0; i < 2; i++)
    #pragma unroll
    for (int j = 0; j < 2; j++)
      #pragma unroll
      for (int r = 0; r < 4; r++)
        Y[(size_t)(row0 + i * 16 + frq + r) * 2048 + col0 + j * 16 + fc] = acc[i][j][r];
}

// ---------------- A-prep (elementwise): A[b,t,h] = gelu(Y[t][b*512+h] + d*xn) ----------------
__global__ __launch_bounds__(256) void aprep_kernel(const float* __restrict__ Y,
    const float* __restrict__ xn, const float* __restrict__ dptr,
    __hip_bfloat16* __restrict__ A) {
  int idx = blockIdx.x * 256 + threadIdx.x;       // 2M
  int h = idx & 511;
  int t = (idx >> 9) & 1023;
  int b = idx >> 19;
  float y = Y[(size_t)t * 2048 + b * 512 + h] + dptr[0] * xn[idx];
  float tnh = tanhf(0.7978845608028654f * (y + 0.044715f * y * y * y));
  float gl = 0.5f * y * (1.0f + tnh);
  A[idx] = __float2bfloat16(gl);
}

// ---- Proj GEMM: C[4096,1024] = A[4096,512] * W[1024,512]^T, weight cvt fused ----
// 64x64 tiles, grid (16,64) = 1024 blocks (4/CU).
__global__ __launch_bounds__(256) void gemm_kernel(const __hip_bfloat16* __restrict__ Abf,
    const float* __restrict__ w1, const float* __restrict__ w2,
    float* __restrict__ C) {
  __shared__ ushort sA[64 * 40];
  __shared__ ushort sB[64 * 40];
  int tid = threadIdx.x;
  int lane = tid & 63;
  int wv = tid >> 6;
  int wm = wv >> 1, wn = wv & 1;
  int bm = blockIdx.y, bn = blockIdx.x;   // bm<64 (m tiles), bn<16 (n tiles)
  floatx4 acc[2][2] = {};
  int srow = tid >> 2;
  int scol = (tid & 3) * 8;
  int fr = lane & 15, fq = (lane >> 4) * 8;
  const ushort* Ag = (const ushort*)Abf + (size_t)(bm * 64) * 512;
  int n = bn * 64 + srow;                 // 0..1023
  const float* Wrow = (n < 512) ? (w1 + (size_t)n * 512) : (w2 + (size_t)(n - 512) * 512);
  for (int kt = 0; kt < 16; kt++) {
    int k0 = kt * 32;
    *(uint4*)&sA[srow * 40 + scol] = *(const uint4*)&Ag[(size_t)srow * 512 + k0 + scol];
    float4 f0 = *(const float4*)&Wrow[k0 + scol];
    float4 f1 = *(const float4*)&Wrow[k0 + scol + 4];
    ushort4 c0, c1;
    ((ushort*)&c0)[0] = f2bf(f0.x); ((ushort*)&c0)[1] = f2bf(f0.y);
    ((ushort*)&c0)[2] = f2bf(f0.z); ((ushort*)&c0)[3] = f2bf(f0.w);
    ((ushort*)&c1)[0] = f2bf(f1.x); ((ushort*)&c1)[1] = f2bf(f1.y);
    ((ushort*)&c1)[2] = f2bf(f1.z); ((ushort*)&c1)[3] = f2bf(f1.w);
    *(ushort4*)&sB[srow * 40 + scol]     = c0;
    *(ushort4*)&sB[srow * 40 + scol + 4] = c1;
    __syncthreads();
    short8 af[2], bf[2];
    #pragma unroll
    for (int i = 0; i < 2; i++) {
      af[i] = *(const short8*)&sA[(wm * 32 + i * 16 + fr) * 40 + fq];
      bf[i] = *(const short8*)&sB[(wn * 32 + i * 16 + fr) * 40 + fq];
    }
    #pragma unroll
    for (int i = 0; i < 2; i++)
      #pragma unroll
      for (int j = 0; j < 2; j++)
        acc[i][j] = __builtin_amdgcn_mfma_f32_16x16x32_bf16(af[i], bf[j], acc[i][j], 0, 0, 0);
    __syncthreads();
  }
  int row0 = bm * 64 + wm * 32;
  int col0 = bn * 64 + wn * 32;
  int fc = lane & 15, frq = (lane >> 4) * 4;
  #pragma unroll
  for (int i = 0; i < 2; i++)
    #pragma unroll
    for (int j = 0; j < 2; j++)
      #pragma unroll
      for (int r = 0; r < 4; r++)
        C[(size_t)(row0 + i * 16 + frq + r) * 1024 + col0 + j * 16 + fc] = acc[i][j][r];
}

// ---------------- Final: out = x + (C1 + ob) * sigmoid(C2 + o2b) ----------------
__global__ __launch_bounds__(256) void final_kernel(const float* __restrict__ x,
    const float* __restrict__ C, const float* __restrict__ ob,
    const float* __restrict__ o2b, float* __restrict__ out) {
  int idx = blockIdx.x * 256 + threadIdx.x;
  int i = idx & 511;
  int bt = idx >> 9;
  float c1 = C[(size_t)bt * 1024 + i] + ob[i];
  float c2 = C[(size_t)bt * 1024 + 512 + i] + o2b[i];
  float gate = 1.0f / (1.0f + expf(-c2));
  out[idx] = x[idx] + c1 * gate;
}

extern "C" void kernel_launch(void* const* d_in, const int* in_sizes, int n_in,
                              void* d_out, int out_size, void* d_ws, size_t ws_size,
                              hipStream_t stream) {
  const float* x   = (const float*)d_in[0];
  const float* nw  = (const float*)d_in[1];
  const float* nb  = (const float*)d_in[2];
  const float* lre = (const float*)d_in[3];
  const float* lim = (const float*)d_in[4];
  const float* pre = (const float*)d_in[5];
  const float* pim = (const float*)d_in[6];
  const float* bre = (const float*)d_in[7];
  const float* bim = (const float*)d_in[8];
  const float* cre = (const float*)d_in[9];
  const float* cim = (const float*)d_in[10];
  const float* dsc = (const float*)d_in[11];
  const float* lst = (const float*)d_in[12];
  const float* w1  = (const float*)d_in[13];
  const float* ob  = (const float*)d_in[14];
  const float* w2  = (const float*)d_in[15];
  const float* o2b = (const float*)d_in[16];

  char* ws = (char*)d_ws;
  // Layout (32 MB total, time-multiplexed):
  float* xn   = (float*)(ws);                              // 0..8MB   (live: ln..aprep)
  float* Yc   = (float*)(ws + (size_t)(8  << 20));         // 8..16MB  (conv out; live conv..aprep)
  float* Kbuf = (float*)(ws + (size_t)(8  << 20) + 65536); // K[1024] (consumed before conv writes Yc)
  ushort* Uhi = (ushort*)(ws + (size_t)(16 << 20));        // 16..20MB
  ushort* Ulo = (ushort*)(ws + (size_t)(20 << 20));        // 20..24MB
  ushort* Thi = (ushort*)(ws + (size_t)(24 << 20));        // 24..26MB
  ushort* Tlo = (ushort*)(ws + (size_t)(26 << 20));        // 26..28MB
  __hip_bfloat16* Abuf = (__hip_bfloat16*)(ws + (size_t)(28 << 20)); // 28..32MB
  float* C    = (float*)(ws + (size_t)(8 << 20));          // 8..24MB (after aprep)
  float* out  = (float*)d_out;

  ln_kernel<<<dim3(4096), dim3(64), 0, stream>>>(x, nw, nb, xn);
  kgen_kernel<<<dim3(1), dim3(512), 0, stream>>>(lre, lim, pre, pim, bre, bim,
                                                 cre, cim, lst, Kbuf);
  toeplitz_kernel<<<dim3(1024), dim3(256), 0, stream>>>(Kbuf, Thi, Tlo);
  transpose_kernel<<<dim3(8, 16, 4), dim3(256), 0, stream>>>(xn, Uhi, Ulo);
  conv_gemm_kernel<<<dim3(32, 16), dim3(256), 0, stream>>>(Thi, Tlo, Uhi, Ulo, Yc);
  aprep_kernel<<<dim3(8192), dim3(256), 0, stream>>>(Yc, xn, dsc, Abuf);
  gemm_kernel<<<dim3(16, 64), dim3(256), 0, stream>>>(Abuf, w1, w2, C);
  final_kernel<<<dim3(8192), dim3(256), 0, stream>>>(x, C, ob, o2b, out);
}